// Round 4
// baseline (299.474 us; speedup 1.0000x reference)
//
#include <hip/hip_runtime.h>

// Temporal shift: B=64, T=128, N=21, C=256, U=1.
// Partitions of C: [0,86) shift -1 (out[t]=x[t+1]); [86,171) shift 0;
// [171,256) shift +1 (out[t]=x[t-1]). Zero-fill out-of-range t.
// Layout (B,T,N,C) row-major: t-stride = N*C = 5376 floats = 1344 float4.
//
// v5 design — v3's branch-free blend + batch-stride loop (amortize all setup):
//  - v3 post-mortem (~69us slice): best so far. v4's exec-predicated B-load +
//    2-elem split regressed (exec-mask churn; MLP was never the limiter).
//  - Residual overhead in v3: every float4 re-pays /21 magic-mul, shift
//    classification, validity selects, and bounds check.
//  - Here each thread owns one position within a single batch element
//    (172,032 float4 = one full (T,N,C) slice) and strides by exactly that
//    amount across all B=64 batch elements. t, c4, shifts, validity, and
//    both load offsets are iteration-INVARIANT -> computed once, amortized
//    64x. Inner loop is a pure fixed-offset copy: 2 loads (same address on
//    62/64 lanes -> L1 hit) + component blend + contiguous 1024B wave store.
//  - #pragma unroll 4: 8 independent loads per window, deep MLP at low VGPR.
//  - Grid 672 blocks x 256 thr = 172,032 threads exactly; no bounds check.

typedef float v4f __attribute__((ext_vector_type(4)));

#define NT_T 128
#define NT_N 21
#define NT_C 256
#define T_STRIDE_V (NT_N * NT_C / 4)            // 1344 float4 per t step
#define B_STRIDE_V (T_STRIDE_V * NT_T)          // 172032 float4 per batch elem
#define NB 64

__global__ __launch_bounds__(256) void temporal_shift_kernel(
    const v4f* __restrict__ xv, v4f* __restrict__ ov)
{
    const int base = blockIdx.x * 256 + threadIdx.x;   // [0, 172032)

    const int c4  = base & 63;              // float4-group within C row
    const int row = base >> 6;              // (t,n) row index, [0, 2688)
    const int t   = row / NT_N;             // [0,128), exact (2688 = 128*21)

    // Component shifts: s(c) = c<86 ? -1 : c<171 ? 0 : +1.
    // comps 0..1 share s0; comp 2 differs only at c4==21; comp 3 differs at
    // c4==21 and c4==42.
    const int c0 = c4 << 2;
    const int s0 = (c0 < 86) ? -1 : ((c0 < 171) ? 0 : 1);
    const int s3 = (c0 + 3 < 86) ? -1 : ((c0 + 3 < 171) ? 0 : 1);

    const bool vA = ((unsigned)(t - s0)) < (unsigned)NT_T;
    const bool vB = ((unsigned)(t - s3)) < (unsigned)NT_T;
    const int offA = vA ? -s0 * T_STRIDE_V : 0;   // clamped in-bounds
    const int offB = vB ? -s3 * T_STRIDE_V : 0;

    const bool z2 = (c4 == 21);     // comp 2 comes from B only on group 21
    const bool z3 = (s3 != s0);     // comp 3 comes from B on groups 21, 42

    const v4f zero = {0.f, 0.f, 0.f, 0.f};

    int j = base;
    #pragma unroll 4
    for (int b = 0; b < NB; ++b) {
        v4f A = xv[j + offA];
        v4f B = xv[j + offB];     // same addr as A on 62/64 lanes -> L1 hit
        if (!vA) A = zero;
        if (!vB) B = zero;
        v4f r;
        r.x = A.x;
        r.y = A.y;
        r.z = z2 ? B.z : A.z;
        r.w = z3 ? B.w : A.w;
        ov[j] = r;
        j += B_STRIDE_V;
    }
}

extern "C" void kernel_launch(void* const* d_in, const int* in_sizes, int n_in,
                              void* d_out, int out_size, void* d_ws, size_t ws_size,
                              hipStream_t stream)
{
    const v4f* x = (const v4f*)d_in[0];
    v4f* out = (v4f*)d_out;
    const int grid = B_STRIDE_V / 256;   // 672 blocks, exact
    temporal_shift_kernel<<<grid, 256, 0, stream>>>(x, out);
}

// Round 5
// 292.709 us; speedup vs baseline: 1.0231x; 1.0231x over previous
//
#include <hip/hip_runtime.h>

// Temporal shift: B=64, T=128, N=21, C=256, U=1.
// Partitions of C: [0,86) shift -1 (out[t]=x[t+1]); [86,171) shift 0;
// [171,256) shift +1 (out[t]=x[t-1]). Zero-fill out-of-range t.
// Layout (B,T,N,C) row-major: t-stride = N*C = 5376 floats = 1344 float4.
//
// v6 design — v3 (best, ~70us slice) with the B-load compacted:
//  - v3's request budget per wave: A-load 3 segments (~11 lines, inherent:
//    three t-shifted read streams) + B-load ANOTHER 3-segment full-row read
//    (~11 lines of TA/TCP request cycles, though L1-hit) + 8-line store.
//  - One wave == one (b,t,n) row (64 lanes x 1 float4 = 256 channels), so
//    the B data actually consumed per wave is only 3 floats:
//      lane 21 needs x[t, c86..87]   (its s=0 half; float4 at row+21 = i)
//      lane 42 needs x[t-1, c171]    (its s=+1 component; float4 at i-1344)
//    -> lanes != 42 all load the SAME float4 xv[row+21] (broadcast, 1 line;
//       for lane 21 that IS its fix-up), lane 42 loads its t-1 float4
//       (1 line). B-load footprint: 11 lines -> 2 lines. No exec branch.
//  - v4/v5 lessons kept: no predication (exec churn), balanced exact grid
//    (43008 blocks = 168/CU), one element per thread, cached stores.

typedef float v4f __attribute__((ext_vector_type(4)));

#define NT_T 128
#define NT_N 21
#define NT_C 256
#define T_STRIDE_V (NT_N * NT_C / 4)   // 1344 float4 per t step

__global__ __launch_bounds__(256) void temporal_shift_kernel(
    const v4f* __restrict__ xv, v4f* __restrict__ ov)
{
    const int i = blockIdx.x * 256 + threadIdx.x;   // exact grid, no tail

    const int c4  = i & 63;          // float4-group within C (64 per row)
    const int row = i >> 6;          // (b,t,n) row index; one wave = one row
    const int t   = (row / NT_N) & (NT_T - 1);

    // Majority shift for this float4 group (components 0..1 always agree):
    //   s(c) = c<86 ? -1 : c<171 ? 0 : +1, evaluated at c0 = 4*c4.
    const int c0 = c4 << 2;
    const int s0 = (c0 < 86) ? -1 : ((c0 < 171) ? 0 : 1);
    const bool vA = ((unsigned)(t - s0)) < (unsigned)NT_T;
    const int offA = vA ? -s0 * T_STRIDE_V : 0;    // clamped in-bounds

    // Compact fix-up load B (2 cache lines per wave):
    //   lane 42: float4 at (t-1, c4=42)  [clamped to t when t==0, zeroed]
    //   others : float4 at (t,   c4=21)  [broadcast; lane 21's s=0 source]
    const int row_v = i - c4;                       // row * 64
    const bool is42 = (c4 == 42);
    const bool vB   = is42 ? (t > 0) : true;
    const int bofs  = is42 ? (vB ? 42 - T_STRIDE_V : 42) : 21;

    v4f A = xv[i + offA];
    v4f B = xv[row_v + bofs];

    const v4f zero = {0.f, 0.f, 0.f, 0.f};
    if (!vA) A = zero;
    if (!vB) B = zero;

    // Blend: only group 21 takes components z,w from B (its s=0 half);
    // only group 42 takes component w from B (its s=+1 single channel).
    v4f r;
    r.x = A.x;
    r.y = A.y;
    r.z = (c4 == 21) ? B.z : A.z;
    r.w = (c4 == 21 || is42) ? B.w : A.w;

    ov[i] = r;
}

extern "C" void kernel_launch(void* const* d_in, const int* in_sizes, int n_in,
                              void* d_out, int out_size, void* d_ws, size_t ws_size,
                              hipStream_t stream)
{
    const v4f* x = (const v4f*)d_in[0];
    v4f* out = (v4f*)d_out;
    const int total_vec = out_size / 4;        // 11,010,048 float4
    const int grid = total_vec / 256;          // 43008 blocks, exact & balanced
    temporal_shift_kernel<<<grid, 256, 0, stream>>>(x, out);
}

// Round 6
// 290.285 us; speedup vs baseline: 1.0317x; 1.0083x over previous
//
#include <hip/hip_runtime.h>

// Temporal shift: B=64, T=128, N=21, C=256, U=1.
// Partitions of C: [0,86) shift -1 (out[t]=x[t+1]); [86,171) shift 0;
// [171,256) shift +1 (out[t]=x[t-1]). Zero-fill out-of-range t.
// Layout (B,T,N,C) row-major: t-stride = N*C = 5376 floats = 1344 float4.
//
// v7 = v3 (best structure, ~71us kernel slice) + non-temporal stores.
//  - v3..v6 post-mortems: structural levers exhausted — MLP (v4), setup
//    amortization (v5), request compaction (v6) all null/negative. The
//    branch-free dual-load blend with one float4/thread is the best shape.
//  - Residual theory: FETCH_SIZE=108MB vs 176MB ideal shows ~39% of input
//    reads hit L3. The 176MB output stream is never re-read, yet regular
//    stores write-allocate in L2/L3, evicting input lines and adding
//    read/write turnaround. nt-store = no-allocate/evict-first: output
//    streams to HBM, L2/L3 capacity stays with the input stream.
//    (v2's nt-store regression was confounded by its divergent 3-branch
//    structure; this isolates the store policy on the good structure.)
//  - Loads stay cached: we WANT the input L3 hits.

typedef float v4f __attribute__((ext_vector_type(4)));

#define NT_T 128
#define NT_N 21
#define NT_C 256
#define T_STRIDE_V (NT_N * NT_C / 4)   // 1344 float4 per t step

__global__ __launch_bounds__(256) void temporal_shift_kernel(
    const v4f* __restrict__ xv, v4f* __restrict__ ov)
{
    const int i = blockIdx.x * 256 + threadIdx.x;   // exact grid, no tail

    const int c4  = i & 63;          // C/4 = 64 float4-groups per (b,t,n) row
    const int row = i >> 6;          // (b,t,n) row index
    const int t   = (row / NT_N) & (NT_T - 1);   // compiler magic-muls /21

    // Per-component shifts from channel c = 4*c4 + k:
    //   s(c) = c<86 ? -1 : c<171 ? 0 : +1
    // Components 0..1 always share s0; component 2 differs only at c4==21;
    // component 3 differs at c4==21 and c4==42.
    const int c0 = c4 << 2;
    const int s0 = (c0 < 86) ? -1 : ((c0 < 171) ? 0 : 1);
    const int s3 = (c0 + 3 < 86) ? -1 : ((c0 + 3 < 171) ? 0 : 1);

    const bool vA = ((unsigned)(t - s0)) < (unsigned)NT_T;
    const bool vB = ((unsigned)(t - s3)) < (unsigned)NT_T;

    // Clamp invalid addresses in-bounds; result masked to zero below.
    v4f A = xv[i - (vA ? s0 : 0) * T_STRIDE_V];
    v4f B = xv[i - (vB ? s3 : 0) * T_STRIDE_V];  // same addr as A on 62/64 lanes

    const v4f zero = {0.f, 0.f, 0.f, 0.f};
    if (!vA) A = zero;
    if (!vB) B = zero;

    v4f r;
    r.x = A.x;
    r.y = A.y;
    r.z = (c4 == 21) ? B.z : A.z;   // only group 21 splits at component 2
    r.w = (s3 != s0) ? B.w : A.w;   // groups 21 and 42 split at component 3

    __builtin_nontemporal_store(r, &ov[i]);
}

extern "C" void kernel_launch(void* const* d_in, const int* in_sizes, int n_in,
                              void* d_out, int out_size, void* d_ws, size_t ws_size,
                              hipStream_t stream)
{
    const v4f* x = (const v4f*)d_in[0];
    v4f* out = (v4f*)d_out;
    const int total_vec = out_size / 4;        // 11,010,048 float4
    const int grid = total_vec / 256;          // 43008 blocks, exact & balanced
    temporal_shift_kernel<<<grid, 256, 0, stream>>>(x, out);
}